// Round 19
// baseline (133.837 us; speedup 1.0000x reference)
//
#include <hip/hip_runtime.h>
#include <math.h>

typedef float vf2 __attribute__((ext_vector_type(2)));

// ---------------- packed dual-fp32 helpers (VOP3P) ----------------
__device__ __forceinline__ vf2 pk_fma(vf2 a, vf2 b, vf2 c) {
    vf2 d;
    asm("v_pk_fma_f32 %0, %1, %2, %3" : "=v"(d) : "v"(a), "v"(b), "v"(c));
    return d;
}
__device__ __forceinline__ vf2 pk_mul(vf2 a, vf2 b) {
    vf2 d;
    asm("v_pk_mul_f32 %0, %1, %2" : "=v"(d) : "v"(a), "v"(b));
    return d;
}
__device__ __forceinline__ vf2 pk_fma_blo(vf2 w, vf2 b, vf2 c) {
    vf2 d;
    asm("v_pk_fma_f32 %0, %1, %2, %3 op_sel_hi:[0,1,1]"
        : "=v"(d) : "v"(w), "v"(b), "v"(c));
    return d;
}
__device__ __forceinline__ vf2 pk_fma_bhi(vf2 w, vf2 b, vf2 c) {
    vf2 d;
    asm("v_pk_fma_f32 %0, %1, %2, %3 op_sel:[1,0,0] op_sel_hi:[1,1,1]"
        : "=v"(d) : "v"(w), "v"(b), "v"(c));
    return d;
}

#define L0_SEG 64
#define NCHUNK 7
#define ROWW 536                    // 268 staged cols x (P,Q) words
#define NQ 134                      // quads per row
#define STREAM_BUF (11 * ROWW)      // 5896 words

#define TILE 32
#define IN_DIM 42
#define SCP 21
#define HALO 10
#define LV_STAGE (IN_DIM * SCP * 4) // 3528
#define SH 340
#define HB LV_STAGE
#define MEGA_WORDS (HB + 16 * SH)   // 8968 words = 35872 B -> 4 blocks/CU

// ================= cascade: originals -> X,Y,Z,W =================
// Block = (plane, region): region r owns X rows [16r,16r+16) x 256 cols.
// X value == L0's old fused pool (P per pixel, 2x2 sum, x0.25) — bit-identical.
// Y/Z/W derived with the same op order as r17/r18. 768 blocks.
__global__ __launch_bounds__(256)
void msssim_cascade(const float* __restrict__ img1, const float* __restrict__ img2,
                    float* __restrict__ X1, float* __restrict__ X2,
                    float* __restrict__ Y1, float* __restrict__ Y2,
                    float* __restrict__ Z1, float* __restrict__ Z2,
                    float* __restrict__ W1, float* __restrict__ W2)
{
    __shared__ float xs[16 * 256 * 2];   // X band (P,Q interleaved)
    __shared__ float ysh[8 * 128 * 2];
    __shared__ float zsh[4 * 64 * 2];
    const int tid = threadIdx.x;
    const int reg = blockIdx.x & 15, plane = blockIdx.x >> 4;
    const long long obase = (long long)plane * 262144;

    for (int i = tid; i < 16 * 256; i += 256) {
        const int r = i >> 8, c = i & 255;
        const long long o = obase + (long long)(2 * (16 * reg + r)) * 512 + 2 * c;
        const float2 a0 = *(const float2*)&img1[o];
        const float2 a1 = *(const float2*)&img1[o + 512];
        const float2 b0 = *(const float2*)&img2[o];
        const float2 b1 = *(const float2*)&img2[o + 512];
        const float P = 0.25f * ((a0.x + b0.x) + (a0.y + b0.y) + (a1.x + b1.x) + (a1.y + b1.y));
        const float Q = 0.25f * ((a0.x - b0.x) + (a0.y - b0.y) + (a1.x - b1.x) + (a1.y - b1.y));
        xs[2 * i] = P; xs[2 * i + 1] = Q;
        const long long xo = (long long)plane * 65536 + (long long)(16 * reg + r) * 256 + c;
        X1[xo] = P; X2[xo] = Q;
    }
    __syncthreads();
    for (int i = tid; i < 8 * 128; i += 256) {
        const int r = i >> 7, c = i & 127;
        const int i00 = ((2 * r) * 256 + 2 * c) * 2;
        const float yP = 0.25f * (xs[i00] + xs[i00 + 2] + xs[i00 + 512] + xs[i00 + 514]);
        const float yQ = 0.25f * (xs[i00 + 1] + xs[i00 + 3] + xs[i00 + 513] + xs[i00 + 515]);
        ysh[2 * i] = yP; ysh[2 * i + 1] = yQ;
        const long long yo = (long long)plane * 16384 + (long long)(8 * reg + r) * 128 + c;
        Y1[yo] = yP; Y2[yo] = yQ;
    }
    __syncthreads();
    for (int i = tid; i < 4 * 64; i += 256) {
        const int r = i >> 6, c = i & 63;
        const int i00 = ((2 * r) * 128 + 2 * c) * 2;
        const float zP = 0.25f * (ysh[i00] + ysh[i00 + 2] + ysh[i00 + 256] + ysh[i00 + 258]);
        const float zQ = 0.25f * (ysh[i00 + 1] + ysh[i00 + 3] + ysh[i00 + 257] + ysh[i00 + 259]);
        zsh[2 * i] = zP; zsh[2 * i + 1] = zQ;
        const long long zo = (long long)plane * 4096 + (long long)(4 * reg + r) * 64 + c;
        Z1[zo] = zP; Z2[zo] = zQ;
    }
    __syncthreads();
    for (int i = tid; i < 2 * 32; i += 256) {
        const int r = i >> 5, c = i & 31;
        const int i00 = ((2 * r) * 64 + 2 * c) * 2;
        const long long wo = (long long)plane * 1024 + (long long)(2 * reg + r) * 32 + c;
        W1[wo] = 0.25f * (zsh[i00] + zsh[i00 + 2] + zsh[i00 + 128] + zsh[i00 + 130]);
        W2[wo] = 0.25f * (zsh[i00 + 1] + zsh[i00 + 3] + zsh[i00 + 129] + zsh[i00 + 131]);
    }
}

// ================= MEGA: L0-stream(768) + L1-stream(192) + L2-4 phase(1008) ==
// L0 streams from originals (forms P,Q); L1 streams from X (pq direct) —
// 1/4 of L0's cost, streaming structure (no h round-trip). L2-4 = phase
// kernel on Y/Z/W. All roles independent; LDS union 35.9KB -> 4 blocks/CU.
__global__ __launch_bounds__(256)
void msssim_mega(const float* __restrict__ img1, const float* __restrict__ img2,
                 const float* __restrict__ X1, const float* __restrict__ X2,
                 const float* __restrict__ Y1, const float* __restrict__ Y2,
                 const float* __restrict__ Z1, const float* __restrict__ Z2,
                 const float* __restrict__ W1, const float* __restrict__ W2,
                 double* __restrict__ sums)
{
    __shared__ __align__(16) float smem[MEGA_WORDS];
    __shared__ float wred[4][2];

    const float gs[11] = {0.00102838f, 0.00759875f, 0.03600077f, 0.10936070f,
                          0.21300554f, 0.26601173f, 0.21300554f, 0.10936070f,
                          0.03600077f, 0.00759875f, 0.00102838f};
    const int tid = threadIdx.x;
    const int bid = blockIdx.x;
    const float C1 = 4.0e-4f, C2 = 3.6e-3f;
    float ssim_acc = 0.f, cs_acc = 0.f;
    int level;

    if (bid < 960) {
        // =============== streaming role (L0: bid<768, L1: 768..960) ===============
        const float *s1, *s2;
        int H, Hout, c0, oy0;
        long long plane;
        bool pq;
        if (bid < 768) {
            level = 0; H = 512; Hout = 502; pq = false;
            s1 = img1; s2 = img2;
            c0 = (bid & 1) * 256;
            oy0 = ((bid >> 1) & 7) * L0_SEG;
            plane = (long long)(bid >> 4) * 262144;
        } else {
            const int id = bid - 768;
            level = 1; H = 256; Hout = 246; pq = true;
            s1 = X1; s2 = X2;
            c0 = 0;
            oy0 = (id & 3) * L0_SEG;
            plane = (long long)(id >> 2) * 65536;
        }
        const bool colok = (c0 + tid) < Hout;

        const int par = tid & 1;
        vf2 wp[6];
        #pragma unroll
        for (int jq = 0; jq < 6; ++jq) {
            const int i0 = 2 * jq, i1 = 2 * jq + 1;
            const float we0 = (i0 < 11) ? gs[i0] : 0.f;
            const float wo0 = (i0 >= 1) ? gs[i0 - 1] : 0.f;
            const float we1 = (i1 < 11) ? gs[i1] : 0.f;
            const float wo1 = (i1 >= 1) ? gs[i1 - 1] : 0.f;
            wp[jq].x = par ? wo0 : we0;
            wp[jq].y = par ? wo1 : we1;
        }
        vf2 wgv[6];
        #pragma unroll
        for (int k = 0; k < 6; ++k) { wgv[k].x = gs[k]; wgv[k].y = gs[k]; }

        int rowS[6], colS[6], ldsoff[6], rHS[6];
        #pragma unroll
        for (int t = 0; t < 6; ++t) {
            const int s = tid + 256 * t;
            if (s < 11 * NQ) {
                const int r = s / NQ, q = s - NQ * r;
                rowS[t] = r; colS[t] = c0 + 2 * q;
                ldsoff[t] = r * ROWW + q * 4; rHS[t] = r * H;
            } else { rowS[t] = -1; colS[t] = 0; ldsoff[t] = 0; rHS[t] = 0; }
        }

        float4 pf[6];
        auto prefetch = [&](int ybase) {
            const long long yH = plane + (long long)ybase * H;
            #pragma unroll
            for (int t = 0; t < 6; ++t) {
                float2 a = make_float2(0.f, 0.f), b = make_float2(0.f, 0.f);
                if (rowS[t] >= 0) {
                    const int y = ybase + rowS[t];
                    if (y < H && colS[t] < H) {
                        const long long idx = yH + rHS[t] + colS[t];
                        a = *(const float2*)(s1 + idx);
                        b = *(const float2*)(s2 + idx);
                    }
                }
                pf[t] = pq ? make_float4(a.x, b.x, a.y, b.y)
                           : make_float4(a.x + b.x, a.x - b.x, a.y + b.y, a.y - b.y);
            }
        };
        auto stage_write = [&]() {
            #pragma unroll
            for (int t = 0; t < 6; ++t)
                if (rowS[t] >= 0) *(float4*)&smem[ldsoff[t]] = pf[t];
        };

        prefetch(oy0);
        stage_write();
        __syncthreads();

        vf2 pd_pq[11], pd_sq[11];
        #pragma unroll
        for (int s = 0; s < 11; ++s) { pd_pq[s] = (vf2){0.f, 0.f}; pd_sq[s] = (vf2){0.f, 0.f}; }

        const int qb4 = (tid >> 1) * 4;

        for (int c = 0; c < NCHUNK; ++c) {
            const bool more = (c + 1 < NCHUNK);
            if (more) prefetch(oy0 + 11 * (c + 1));

            #pragma unroll
            for (int j = 0; j < 11; ++j) {
                pd_pq[j] = (vf2){0.f, 0.f};
                pd_sq[j] = (vf2){0.f, 0.f};

                float4 q[6];
                const int rw = j * ROWW + qb4;
                #pragma unroll
                for (int u = 0; u < 6; ++u) q[u] = *(const float4*)&smem[rw + 4 * u];

                vf2 hpq = {0.f, 0.f}, hsq = {0.f, 0.f};
                #pragma unroll
                for (int u = 0; u < 6; ++u) {
                    const vf2 elo = {q[u].x, q[u].y};
                    const vf2 ehi = {q[u].z, q[u].w};
                    const vf2 slo = pk_mul(elo, elo);
                    const vf2 shi = pk_mul(ehi, ehi);
                    hpq = pk_fma_blo(wp[u], elo, hpq);
                    hpq = pk_fma_bhi(wp[u], ehi, hpq);
                    hsq = pk_fma_blo(wp[u], slo, hsq);
                    hsq = pk_fma_bhi(wp[u], shi, hsq);
                }
                #pragma unroll
                for (int k = 0; k < 11; ++k) {
                    const int s = (j - k + 11) % 11;
                    const int m = (k <= 5) ? k : 10 - k;
                    pd_pq[s] = pk_fma(wgv[m], hpq, pd_pq[s]);
                    pd_sq[s] = pk_fma(wgv[m], hsq, pd_sq[s]);
                }
                const int yrel = 11 * c + j;
                if (yrel >= 10) {
                    const int s = (j + 1) % 11;
                    const int orow = yrel - 10;
                    if (orow < L0_SEG && (oy0 + orow) < Hout && colok) {
                        const vf2 musq = pk_mul(pd_pq[s], pd_pq[s]);
                        const float sP = pd_sq[s].x - musq.x;
                        const float sQ = pd_sq[s].y - musq.y;
                        const float v1 = 0.5f * (sP - sQ) + C2;
                        const float v2 = 0.5f * (sP + sQ) + C2;
                        const float num1 = 0.5f * (musq.x - musq.y) + C1;
                        const float den1 = 0.5f * (musq.x + musq.y) + C1;
                        cs_acc += v1 * __builtin_amdgcn_rcpf(v2);
                        ssim_acc += num1 * v1 * __builtin_amdgcn_rcpf(den1 * v2);
                    }
                }
            }

            __syncthreads();
            if (more) stage_write();
            __syncthreads();
        }
    } else {
        // ======================= L2/L3/L4 phase role =======================
        const int id = bid - 960;
        const float *src1, *src2;
        int H, strip, seg, plane;
        if (id < 768) {
            level = 2; H = 128; src1 = Y1; src2 = Y2;
            plane = id >> 4; const int t = id & 15; strip = t & 3; seg = t >> 2;
        } else if (id < 960) {
            level = 3; H = 64; src1 = Z1; src2 = Z2;
            const int r = id - 768; plane = r >> 2; const int t = r & 3; strip = t & 1; seg = t >> 1;
        } else {
            level = 4; H = 32; src1 = W1; src2 = W2;
            plane = id - 960; strip = 0; seg = 0;
        }

        vf2 wg[11];
        #pragma unroll
        for (int k = 0; k < 11; ++k) { wg[k].x = gs[k]; wg[k].y = gs[k]; }

        const int Hout = H - HALO;
        const int ntiles = (Hout + TILE - 1) / TILE;
        const int tstart = seg;
        const int tend = min(ntiles, tstart + 1);
        const int ox0 = strip * TILE;
        const long long base = (long long)plane * H * H;

        int rHS[4], rS[4], xS[4];
        #pragma unroll
        for (int t4 = 0; t4 < 4; ++t4) {
            const int s = tid + 256 * t4;
            if (s < IN_DIM * SCP) {
                const int r = s / SCP, cp = s - r * SCP;
                rS[t4] = r; rHS[t4] = r * H; xS[t4] = ox0 + 2 * cp;
            } else { rS[t4] = -1; rHS[t4] = 0; xS[t4] = 0; }
        }

        auto load_slot = [&](int t4, int ybase) -> float4 {
            if (rS[t4] < 0) return make_float4(0.f, 0.f, 0.f, 0.f);
            const int y = ybase + rS[t4], x = xS[t4];
            if (y >= H || x >= H) return make_float4(0.f, 0.f, 0.f, 0.f);
            const long long idx = base + (long long)ybase * H + rHS[t4] + x;
            const float2 a = *(const float2*)(src1 + idx);
            const float2 b = *(const float2*)(src2 + idx);
            return make_float4(a.x, b.x, a.y, b.y);   // (P0,Q0,P1,Q1)
        };

        float4 pref[4];
        {
            #pragma unroll
            for (int t4 = 0; t4 < 4; ++t4) pref[t4] = load_slot(t4, tstart * TILE);
            #pragma unroll
            for (int t4 = 0; t4 < 4; ++t4)
                if (rS[t4] >= 0) *(float4*)&smem[(tid + 256 * t4) * 4] = pref[t4];
        }
        __syncthreads();

        for (int tt = tstart; tt < tend; ++tt) {
            const int ty0 = tt * TILE;

            float4 hA[3], hBv[3];
            #pragma unroll
            for (int t = 0; t < 3; ++t) {
                const int p = tid + 256 * t;
                if (p < IN_DIM * 16) {
                    const int r = p >> 4, m = p & 15;
                    vf2 Apq = {0.f, 0.f}, Asq = {0.f, 0.f};
                    vf2 Bpq = {0.f, 0.f}, Bsq = {0.f, 0.f};
                    #pragma unroll
                    for (int jj = 0; jj < 6; ++jj) {
                        const float4 v = *(const float4*)&smem[(r * SCP + m + jj) * 4];
                        const vf2 lo = {v.x, v.y};
                        const vf2 hi = {v.z, v.w};
                        const vf2 losq = pk_mul(lo, lo);
                        const vf2 hisq = pk_mul(hi, hi);
                        Apq = pk_fma(wg[2 * jj], lo, Apq);
                        Asq = pk_fma(wg[2 * jj], losq, Asq);
                        if (jj >= 1) {
                            Bpq = pk_fma(wg[2 * jj - 1], lo, Bpq);
                            Bsq = pk_fma(wg[2 * jj - 1], losq, Bsq);
                        }
                        if (jj <= 4) {
                            Apq = pk_fma(wg[2 * jj + 1], hi, Apq);
                            Asq = pk_fma(wg[2 * jj + 1], hisq, Asq);
                        }
                        Bpq = pk_fma(wg[2 * jj], hi, Bpq);
                        Bsq = pk_fma(wg[2 * jj], hisq, Bsq);
                    }
                    hA[t]  = make_float4(Apq.x, Apq.y, Asq.x, Asq.y);
                    hBv[t] = make_float4(Bpq.x, Bpq.y, Bsq.x, Bsq.y);
                }
            }
            __syncthreads();

            #pragma unroll
            for (int t = 0; t < 3; ++t) {
                const int p = tid + 256 * t;
                if (p < IN_DIM * 16) {
                    const int r = p >> 4, m = p & 15;
                    const int hb = HB + m * SH + r * 8;
                    *(float4*)&smem[hb]     = hA[t];
                    *(float4*)&smem[hb + 4] = hBv[t];
                }
            }
            __syncthreads();

            const int tx = tid & 31, rg = tid >> 5;
            const int r0 = rg * 4;
            const int m = tx >> 1, par = tx & 1;
            const int hb = HB + m * SH + par * 4;

            vf2 accPQ[4], accSQ[4];
            #pragma unroll
            for (int o = 0; o < 4; ++o) {
                accPQ[o] = (vf2){0.f, 0.f};
                accSQ[o] = (vf2){0.f, 0.f};
            }
            #pragma unroll
            for (int i = 0; i < 14; ++i) {
                const float4 h4 = *(const float4*)&smem[hb + (r0 + i) * 8];
                const vf2 ppq = {h4.x, h4.y};
                const vf2 psq = {h4.z, h4.w};
                #pragma unroll
                for (int o = 0; o < 4; ++o) {
                    const int k = i - o;
                    if (k >= 0 && k <= 10) {
                        accPQ[o] = pk_fma(wg[k], ppq, accPQ[o]);
                        accSQ[o] = pk_fma(wg[k], psq, accSQ[o]);
                    }
                }
            }

            const int ox = ox0 + tx;
            #pragma unroll
            for (int o = 0; o < 4; ++o) {
                const int oy = ty0 + r0 + o;
                if (oy < Hout && ox < Hout) {
                    const vf2 musq = pk_mul(accPQ[o], accPQ[o]);
                    const float sP = accSQ[o].x - musq.x;
                    const float sQ = accSQ[o].y - musq.y;
                    const float v1 = 0.5f * (sP - sQ) + C2;
                    const float v2 = 0.5f * (sP + sQ) + C2;
                    const float num1 = 0.5f * (musq.x - musq.y) + C1;
                    const float den1 = 0.5f * (musq.x + musq.y) + C1;
                    cs_acc += v1 * __builtin_amdgcn_rcpf(v2);
                    ssim_acc += num1 * v1 * __builtin_amdgcn_rcpf(den1 * v2);
                }
            }
        }
    }

    // ---- block reduction + f64 atomics (all roles)
    #pragma unroll
    for (int off = 32; off > 0; off >>= 1) {
        ssim_acc += __shfl_down(ssim_acc, off);
        cs_acc   += __shfl_down(cs_acc, off);
    }
    const int wave = tid >> 6;
    if ((tid & 63) == 0) { wred[wave][0] = ssim_acc; wred[wave][1] = cs_acc; }
    __syncthreads();
    if (tid == 0) {
        const float s = wred[0][0] + wred[1][0] + wred[2][0] + wred[3][0];
        const float c = wred[0][1] + wred[1][1] + wred[2][1] + wred[3][1];
        atomicAdd(&sums[level],     (double)s);
        atomicAdd(&sums[5 + level], (double)c);
    }
}

// -------------------- final combine --------------------
__global__ void msssim_final_kernel(const double* __restrict__ sums,
                                    float* __restrict__ out)
{
    if (threadIdx.x == 0 && blockIdx.x == 0) {
        const double W[5] = {0.0448, 0.2856, 0.3001, 0.2363, 0.1333};
        const int Houts[5] = {502, 246, 118, 54, 22};
        double mssim[5], mcs[5];
        for (int l = 0; l < 5; ++l) {
            const double cnt = 48.0 * (double)Houts[l] * (double)Houts[l];
            mssim[l] = (sums[l]     / cnt + 1.0) * 0.5;
            mcs[l]   = (sums[5 + l] / cnt + 1.0) * 0.5;
        }
        const double p2 = pow(mssim[4], W[4]);
        double prod = 1.0;
        for (int l = 0; l < 4; ++l) prod *= pow(mcs[l], W[l]) * p2;
        out[0] = (float)(1.0 - prod);
    }
}

// -------------------- launch --------------------
extern "C" void kernel_launch(void* const* d_in, const int* in_sizes, int n_in,
                              void* d_out, int out_size, void* d_ws, size_t ws_size,
                              hipStream_t stream)
{
    const float* img1 = (const float*)d_in[0];
    const float* img2 = (const float*)d_in[1];
    float* out = (float*)d_out;
    (void)in_sizes; (void)n_in; (void)out_size; (void)ws_size;

    char* ws = (char*)d_ws;
    double* sums = (double*)ws;                      // 10 doubles
    float* X1 = (float*)(ws + 256);                  // 48 x 256^2
    float* X2 = X1 + 3145728;
    float* Y1 = X2 + 3145728;                        // 48 x 128^2
    float* Y2 = Y1 + 786432;
    float* Z1 = Y2 + 786432;                         // 48 x 64^2
    float* Z2 = Z1 + 196608;
    float* W1 = Z2 + 196608;                         // 48 x 32^2
    float* W2 = W1 + 49152;

    hipMemsetAsync(sums, 0, 10 * sizeof(double), stream);

    // cascade from originals -> X, Y, Z, W
    hipLaunchKernelGGL(msssim_cascade, dim3(768), dim3(256), 0, stream,
                       img1, img2, X1, X2, Y1, Y2, Z1, Z2, W1, W2);

    // mega: L0-stream (768) + L1-stream (192) + L2/3/4 phase (1008)
    hipLaunchKernelGGL(msssim_mega, dim3(1968), dim3(256), 0, stream,
                       img1, img2, X1, X2, Y1, Y2, Z1, Z2, W1, W2, sums);

    hipLaunchKernelGGL(msssim_final_kernel, dim3(1), dim3(64), 0, stream, sums, out);
}